// Round 1
// baseline (606.150 us; speedup 1.0000x reference)
//
#include <hip/hip_runtime.h>
#include <stdint.h>

#define ALPHA 0.2f
#define LOG2E 1.44269504088896340736f

typedef __attribute__((ext_vector_type(8))) short bf16x8;
typedef __attribute__((ext_vector_type(4))) float f32x4;

__device__ __forceinline__ unsigned short f2bf(float f) {
    unsigned u = __builtin_bit_cast(unsigned, f);
    u += 0x7fffu + ((u >> 16) & 1u);
    return (unsigned short)(u >> 16);
}
__device__ __forceinline__ float bf2f(unsigned short h) {
    unsigned u = ((unsigned)h) << 16;
    return __builtin_bit_cast(float, u);
}
// order-preserving float<->uint mapping for atomicMax over signed floats
__device__ __forceinline__ unsigned f2ord(float f) {
    unsigned b = __builtin_bit_cast(unsigned, f);
    return (b & 0x80000000u) ? ~b : (b | 0x80000000u);
}
__device__ __forceinline__ float ord2f(unsigned k) {
    unsigned b = (k & 0x80000000u) ? (k & 0x7fffffffu) : ~k;
    return __builtin_bit_cast(float, b);
}

// Kernel A: h = input @ W (fp32), att_l/att_r, R = max(att_r), hT hi/lo bf16 (transposed)
__global__ __launch_bounds__(256) void gat_prep(
    const float* __restrict__ input, const float* __restrict__ W,
    const float* __restrict__ a,
    float* __restrict__ attL, float* __restrict__ attR,
    unsigned short* __restrict__ hThi, unsigned short* __restrict__ hTlo,
    unsigned* __restrict__ wsR)
{
    __shared__ float in_lds[16 * 512];
    __shared__ float h_lds[64 * 17];   // padded stride 17: bank-conflict-free transpose
    const int tid = threadIdx.x;
    const int i0  = blockIdx.x * 16;

    // stage 16 input rows (32 KB), fully coalesced float4
    const float* src = input + (size_t)i0 * 512;
    #pragma unroll
    for (int it = 0; it < 8; ++it) {
        const int idx = it * 1024 + tid * 4;
        *(f32x4*)&in_lds[idx] = *(const f32x4*)&src[idx];
    }
    __syncthreads();

    const int c = tid & 63;   // output channel = lane
    const int w = tid >> 6;   // wave id; wave w computes rows {w, w+4, w+8, w+12}
    float acc[4] = {0.f, 0.f, 0.f, 0.f};
    const float* Wc = W + c;
    #pragma unroll 4
    for (int k = 0; k < 512; k += 4) {
        const float w0 = Wc[(k+0)*64], w1 = Wc[(k+1)*64], w2 = Wc[(k+2)*64], w3 = Wc[(k+3)*64];
        #pragma unroll
        for (int ri = 0; ri < 4; ++ri) {
            const f32x4 x = *(const f32x4*)&in_lds[(w + 4*ri) * 512 + k];
            acc[ri] += x.x * w0 + x.y * w1 + x.z * w2 + x.w * w3;
        }
    }

    const float aLc = a[c];
    const float aRc = a[64 + c];
    #pragma unroll
    for (int ri = 0; ri < 4; ++ri) {
        const int r = w + 4*ri;
        float sl = acc[ri] * aLc;
        float sr = acc[ri] * aRc;
        #pragma unroll
        for (int off = 32; off >= 1; off >>= 1) {
            sl += __shfl_xor(sl, off, 64);
            sr += __shfl_xor(sr, off, 64);
        }
        if (c == 0) {
            attL[i0 + r] = sl;
            attR[i0 + r] = sr;
            atomicMax(wsR, f2ord(sr));
        }
        h_lds[c * 17 + r] = acc[ri];   // transpose via LDS
    }
    __syncthreads();

    // write hT hi/lo bf16: row = channel, 16 columns of this block's i-tile
    {
        const int c2 = tid >> 2;
        const int r0 = (tid & 3) * 4;
        ushort4 H, L;
        float v0 = h_lds[c2*17 + r0 + 0], v1 = h_lds[c2*17 + r0 + 1];
        float v2 = h_lds[c2*17 + r0 + 2], v3 = h_lds[c2*17 + r0 + 3];
        H.x = f2bf(v0); H.y = f2bf(v1); H.z = f2bf(v2); H.w = f2bf(v3);
        L.x = f2bf(v0 - bf2f(H.x)); L.y = f2bf(v1 - bf2f(H.y));
        L.z = f2bf(v2 - bf2f(H.z)); L.w = f2bf(v3 - bf2f(H.w));
        *(ushort4*)&hThi[(size_t)c2 * 8192 + i0 + r0] = H;
        *(ushort4*)&hTlo[(size_t)c2 * 8192 + i0 + r0] = L;
    }
}

// Kernel C: fused mask + exp + P@h via MFMA. Block: 16 i-rows x 4096 j-half.
// Each of 4 waves owns a 1024-j chunk; fixed upper-bound M => no online rescale.
__global__ __launch_bounds__(256, 3) void gat_attn(
    const int* __restrict__ adj,
    const float* __restrict__ attL, const float* __restrict__ attR,
    const unsigned short* __restrict__ hThi, const unsigned short* __restrict__ hTlo,
    const unsigned* __restrict__ wsR,
    float* __restrict__ outAcc, float* __restrict__ lAcc)
{
    __shared__ float acc_lds[4 * 64 * 16];
    __shared__ float l_lds[4 * 16];
    const int tid  = threadIdx.x;
    const int lane = tid & 63;
    const int wq   = tid >> 6;
    const int m    = lane & 15;     // MFMA A-row / i-offset
    const int quad = lane >> 4;     // k-subgroup
    const int i0   = (blockIdx.x >> 1) * 16;
    const int jb   = (blockIdx.x & 1) * 4096 + wq * 1024 + quad * 8;

    const float R   = ord2f(*wsR);
    const float a_l = attL[i0 + m];
    const float t0  = a_l + R;
    const float M   = fmaxf(t0, ALPHA * t0);   // row upper bound of e (lrelu monotone)
    const float mc  = M * LOG2E;

    const int*            adj_p = adj  + (size_t)(i0 + m) * 8192 + jb;
    const float*          ar_p  = attR + jb;
    const unsigned short* hh[4];
    const unsigned short* hl[4];
    #pragma unroll
    for (int g = 0; g < 4; ++g) {
        hh[g] = hThi + (size_t)(g * 16 + m) * 8192 + jb;
        hl[g] = hTlo + (size_t)(g * 16 + m) * 8192 + jb;
    }

    f32x4 acc[4];
    #pragma unroll
    for (int g = 0; g < 4; ++g) acc[g] = (f32x4){0.f, 0.f, 0.f, 0.f};
    float lsum = 0.f;

    #pragma unroll 2
    for (int s = 0; s < 32; ++s) {
        const int4  A0 = *(const int4*)(adj_p + s * 32);
        const int4  A1 = *(const int4*)(adj_p + s * 32 + 4);
        const f32x4 r0 = *(const f32x4*)(ar_p + s * 32);
        const f32x4 r1 = *(const f32x4*)(ar_p + s * 32 + 4);
        bf16x8 Bh[4], Bl[4];
        #pragma unroll
        for (int g = 0; g < 4; ++g) {
            Bh[g] = *(const bf16x8*)(hh[g] + s * 32);
            Bl[g] = *(const bf16x8*)(hl[g] + s * 32);
        }

        float pv[8];
        {
            const float t[8] = { a_l + r0.x, a_l + r0.y, a_l + r0.z, a_l + r0.w,
                                 a_l + r1.x, a_l + r1.y, a_l + r1.z, a_l + r1.w };
            const int   av[8] = { A0.x, A0.y, A0.z, A0.w, A1.x, A1.y, A1.z, A1.w };
            #pragma unroll
            for (int u = 0; u < 8; ++u) {
                const float e  = fmaxf(t[u], ALPHA * t[u]);          // leaky_relu
                const float pe = __builtin_amdgcn_exp2f(__builtin_fmaf(e, LOG2E, -mc));
                pv[u] = av[u] ? pe : 0.0f;                           // mask
            }
        }
        bf16x8 af;
        #pragma unroll
        for (int u = 0; u < 8; ++u) {
            const unsigned short b = f2bf(pv[u]);
            af[u] = (short)b;
            lsum += bf2f(b);   // denominator from the SAME rounded weights
        }
        #pragma unroll
        for (int g = 0; g < 4; ++g) {
            acc[g] = __builtin_amdgcn_mfma_f32_16x16x32_bf16(af, Bh[g], acc[g], 0, 0, 0);
            acc[g] = __builtin_amdgcn_mfma_f32_16x16x32_bf16(af, Bl[g], acc[g], 0, 0, 0);
        }
    }

    // reduce l across the 4 k-quads (rows live in lanes m, m+16, m+32, m+48)
    lsum += __shfl_xor(lsum, 16, 64);
    lsum += __shfl_xor(lsum, 32, 64);
    if (lane < 16) l_lds[wq * 16 + lane] = lsum;
    #pragma unroll
    for (int g = 0; g < 4; ++g)
        *(f32x4*)&acc_lds[(wq * 64 + lane) * 16 + g * 4] = acc[g];
    __syncthreads();

    // combine 4 waves, scatter partial numerator to global accumulator
    #pragma unroll
    for (int q = 0; q < 4; ++q) {
        const int e      = tid + q * 256;
        const int lane_e = e >> 4;
        const int k16    = e & 15;
        float s = 0.f;
        #pragma unroll
        for (int ww = 0; ww < 4; ++ww) s += acc_lds[(ww * 64 + lane_e) * 16 + k16];
        const int row = (lane_e >> 4) * 4 + (k16 & 3);   // C/D: row = quad*4+reg
        const int col = (k16 >> 2) * 16 + (lane_e & 15); // C/D: col = lane&15 (per n-group)
        unsafeAtomicAdd(&outAcc[(size_t)(i0 + row) * 64 + col], s);
    }
    if (tid < 16) {
        const float s = l_lds[tid] + l_lds[16 + tid] + l_lds[32 + tid] + l_lds[48 + tid];
        unsafeAtomicAdd(&lAcc[i0 + tid], s);
    }
}

// Kernel D: out = elu(numerator / denominator), in place
__global__ __launch_bounds__(256) void gat_final(
    float* __restrict__ out, const float* __restrict__ lAcc)
{
    const int idx = blockIdx.x * 256 + threadIdx.x;
    const float v = out[idx] / lAcc[idx >> 6];
    out[idx] = v > 0.f ? v : expm1f(v);
}

extern "C" void kernel_launch(void* const* d_in, const int* in_sizes, int n_in,
                              void* d_out, int out_size, void* d_ws, size_t ws_size,
                              hipStream_t stream) {
    const float* input = (const float*)d_in[0];   // 8192 x 512 f32
    const int*   adj   = (const int*)d_in[1];     // 8192 x 8192 i32
    const float* W     = (const float*)d_in[2];   // 512 x 64 f32
    const float* a     = (const float*)d_in[3];   // 128 x 1 f32
    float* out = (float*)d_out;                   // 8192 x 64 f32

    char* ws = (char*)d_ws;
    unsigned*       wsR  = (unsigned*)(ws + 0);          // 4 B   (ordered-uint max)
    float*          lAcc = (float*)(ws + 4096);          // 32 KB softmax denominators
    float*          attL = (float*)(ws + 36864);         // 32 KB
    float*          attR = (float*)(ws + 69632);         // 32 KB
    unsigned short* hThi = (unsigned short*)(ws + 102400);   // 1 MB  hT hi bf16
    unsigned short* hTlo = (unsigned short*)(ws + 1150976);  // 1 MB  hT lo bf16

    // zero the accumulators (ws/out are poisoned 0xAA before every call)
    hipMemsetAsync(d_out, 0, (size_t)out_size * sizeof(float), stream);
    hipMemsetAsync(d_ws, 0, 36864, stream);

    gat_prep<<<512, 256, 0, stream>>>(input, W, a, attL, attR, hThi, hTlo, wsR);
    gat_attn<<<1024, 256, 0, stream>>>(adj, attL, attR, hThi, hTlo, wsR, out, lAcc);
    gat_final<<<2048, 256, 0, stream>>>(out, lAcc);
}

// Round 2
// 564.046 us; speedup vs baseline: 1.0746x; 1.0746x over previous
//
#include <hip/hip_runtime.h>
#include <stdint.h>

#define ALPHA 0.2f
#define LOG2E 1.44269504088896340736f

typedef __attribute__((ext_vector_type(8))) short bf16x8;
typedef __attribute__((ext_vector_type(4))) float f32x4;

__device__ __forceinline__ unsigned short f2bf(float f) {
    unsigned u = __builtin_bit_cast(unsigned, f);
    u += 0x7fffu + ((u >> 16) & 1u);
    return (unsigned short)(u >> 16);
}
__device__ __forceinline__ float bf2f(unsigned short h) {
    unsigned u = ((unsigned)h) << 16;
    return __builtin_bit_cast(float, u);
}
// order-preserving float<->uint mapping for atomicMax over signed floats
__device__ __forceinline__ unsigned f2ord(float f) {
    unsigned b = __builtin_bit_cast(unsigned, f);
    return (b & 0x80000000u) ? ~b : (b | 0x80000000u);
}
__device__ __forceinline__ float ord2f(unsigned k) {
    unsigned b = (k & 0x80000000u) ? (k & 0x7fffffffu) : ~k;
    return __builtin_bit_cast(float, b);
}

// Kernel A: h = input @ W (fp32), att_l/att_r, R = max(att_r), hT hi/lo bf16 (transposed).
// W staged through LDS in 64-k chunks; input rows read as wave-broadcast loads
// (all 64 lanes same address -> 1 transaction); ONE global atomicMax per block.
__global__ __launch_bounds__(256) void gat_prep(
    const float* __restrict__ input, const float* __restrict__ W,
    const float* __restrict__ a,
    float* __restrict__ attL, float* __restrict__ attR,
    unsigned short* __restrict__ hThi, unsigned short* __restrict__ hTlo,
    unsigned* __restrict__ wsR)
{
    __shared__ float w_lds[64 * 64];   // one k-chunk of W, [kk][c] (c = lane -> conflict-free)
    __shared__ float h_lds[64 * 17];   // padded transpose buffer
    __shared__ unsigned rmax;
    const int tid = threadIdx.x;
    const int i0  = blockIdx.x * 16;
    const int c   = tid & 63;   // output channel = lane
    const int w   = tid >> 6;   // wave id; wave w computes rows {w, w+4, w+8, w+12}

    if (tid == 0) rmax = 0u;    // 0 is the identity of the f2ord ordering

    float acc[4] = {0.f, 0.f, 0.f, 0.f};
    const float* in0 = input + (size_t)i0 * 512;

    for (int k0 = 0; k0 < 512; k0 += 64) {
        __syncthreads();
        #pragma unroll
        for (int it = 0; it < 4; ++it) {
            const int idx = it * 1024 + tid * 4;
            *(f32x4*)&w_lds[idx] = *(const f32x4*)&W[k0 * 64 + idx];
        }
        __syncthreads();
        #pragma unroll 4
        for (int kk = 0; kk < 64; kk += 4) {
            const float w0 = w_lds[(kk+0)*64 + c], w1 = w_lds[(kk+1)*64 + c];
            const float w2 = w_lds[(kk+2)*64 + c], w3 = w_lds[(kk+3)*64 + c];
            #pragma unroll
            for (int ri = 0; ri < 4; ++ri) {
                const f32x4 x = *(const f32x4*)&in0[(w + 4*ri) * 512 + k0 + kk];
                acc[ri] += x.x * w0 + x.y * w1 + x.z * w2 + x.w * w3;
            }
        }
    }

    const float aLc = a[c];
    const float aRc = a[64 + c];
    #pragma unroll
    for (int ri = 0; ri < 4; ++ri) {
        const int r = w + 4*ri;
        float sl = acc[ri] * aLc;
        float sr = acc[ri] * aRc;
        #pragma unroll
        for (int off = 32; off >= 1; off >>= 1) {
            sl += __shfl_xor(sl, off, 64);
            sr += __shfl_xor(sr, off, 64);
        }
        if (c == 0) {
            attL[i0 + r] = sl;
            attR[i0 + r] = sr;
            atomicMax(&rmax, f2ord(sr));   // LDS atomic, per-block
        }
        h_lds[c * 17 + r] = acc[ri];       // transpose via LDS
    }
    __syncthreads();
    if (tid == 0) atomicMax(wsR, rmax);    // ONE global atomic per block

    // write hT hi/lo bf16: row = channel, 16 columns of this block's i-tile
    {
        const int c2 = tid >> 2;
        const int r0 = (tid & 3) * 4;
        ushort4 H, L;
        float v0 = h_lds[c2*17 + r0 + 0], v1 = h_lds[c2*17 + r0 + 1];
        float v2 = h_lds[c2*17 + r0 + 2], v3 = h_lds[c2*17 + r0 + 3];
        H.x = f2bf(v0); H.y = f2bf(v1); H.z = f2bf(v2); H.w = f2bf(v3);
        L.x = f2bf(v0 - bf2f(H.x)); L.y = f2bf(v1 - bf2f(H.y));
        L.z = f2bf(v2 - bf2f(H.z)); L.w = f2bf(v3 - bf2f(H.w));
        *(ushort4*)&hThi[(size_t)c2 * 8192 + i0 + r0] = H;
        *(ushort4*)&hTlo[(size_t)c2 * 8192 + i0 + r0] = L;
    }
}

// Kernel C: fused mask + exp + P@h via MFMA. Block: 16 i-rows x 2048 j-quarter.
// 2048 blocks -> 8 blocks/CU (32 waves/CU) for latency hiding; fixed upper
// bound M (lrelu monotone) => no online rescale, partials combine by addition.
__global__ __launch_bounds__(256, 8) void gat_attn(
    const int* __restrict__ adj,
    const float* __restrict__ attL, const float* __restrict__ attR,
    const unsigned short* __restrict__ hThi, const unsigned short* __restrict__ hTlo,
    const unsigned* __restrict__ wsR,
    float* __restrict__ outAcc, float* __restrict__ lAcc)
{
    __shared__ float acc_lds[4 * 64 * 16];
    __shared__ float l_lds[4 * 16];
    const int tid  = threadIdx.x;
    const int lane = tid & 63;
    const int wq   = tid >> 6;
    const int m    = lane & 15;     // MFMA A-row / i-offset
    const int quad = lane >> 4;     // k-subgroup
    const int i0   = (blockIdx.x >> 2) * 16;
    const int jb   = (blockIdx.x & 3) * 2048 + wq * 512 + quad * 8;

    const float R   = ord2f(*wsR);
    const float a_l = attL[i0 + m];
    const float t0  = a_l + R;
    const float M   = fmaxf(t0, ALPHA * t0);   // row upper bound of e
    const float mc  = M * LOG2E;

    const int*            adj_p = adj  + (size_t)(i0 + m) * 8192 + jb;
    const float*          ar_p  = attR + jb;
    const unsigned short* hh[4];
    const unsigned short* hl[4];
    #pragma unroll
    for (int g = 0; g < 4; ++g) {
        hh[g] = hThi + (size_t)(g * 16 + m) * 8192 + jb;
        hl[g] = hTlo + (size_t)(g * 16 + m) * 8192 + jb;
    }

    f32x4 acc[4];
    #pragma unroll
    for (int g = 0; g < 4; ++g) acc[g] = (f32x4){0.f, 0.f, 0.f, 0.f};
    float lsum = 0.f;

    #pragma unroll 2
    for (int s = 0; s < 16; ++s) {
        const int4  A0 = *(const int4*)(adj_p + s * 32);
        const int4  A1 = *(const int4*)(adj_p + s * 32 + 4);
        const f32x4 r0 = *(const f32x4*)(ar_p + s * 32);
        const f32x4 r1 = *(const f32x4*)(ar_p + s * 32 + 4);
        bf16x8 Bh[4], Bl[4];
        #pragma unroll
        for (int g = 0; g < 4; ++g) {
            Bh[g] = *(const bf16x8*)(hh[g] + s * 32);
            Bl[g] = *(const bf16x8*)(hl[g] + s * 32);
        }

        float pv[8];
        {
            const float t[8] = { a_l + r0.x, a_l + r0.y, a_l + r0.z, a_l + r0.w,
                                 a_l + r1.x, a_l + r1.y, a_l + r1.z, a_l + r1.w };
            const int   av[8] = { A0.x, A0.y, A0.z, A0.w, A1.x, A1.y, A1.z, A1.w };
            #pragma unroll
            for (int u = 0; u < 8; ++u) {
                const float e  = fmaxf(t[u], ALPHA * t[u]);          // leaky_relu
                const float pe = __builtin_amdgcn_exp2f(__builtin_fmaf(e, LOG2E, -mc));
                pv[u] = av[u] ? pe : 0.0f;                           // mask
            }
        }
        bf16x8 af;
        float ls0 = 0.f, ls1 = 0.f;
        #pragma unroll
        for (int u = 0; u < 8; u += 2) {
            const unsigned short b0 = f2bf(pv[u]);
            const unsigned short b1 = f2bf(pv[u+1]);
            af[u]   = (short)b0;
            af[u+1] = (short)b1;
            ls0 += bf2f(b0);   // denominator from the SAME rounded weights
            ls1 += bf2f(b1);
        }
        lsum += ls0 + ls1;
        #pragma unroll
        for (int g = 0; g < 4; ++g) {
            acc[g] = __builtin_amdgcn_mfma_f32_16x16x32_bf16(af, Bh[g], acc[g], 0, 0, 0);
            acc[g] = __builtin_amdgcn_mfma_f32_16x16x32_bf16(af, Bl[g], acc[g], 0, 0, 0);
        }
    }

    // reduce l across the 4 k-quads (rows live in lanes m, m+16, m+32, m+48)
    lsum += __shfl_xor(lsum, 16, 64);
    lsum += __shfl_xor(lsum, 32, 64);
    if (lane < 16) l_lds[wq * 16 + lane] = lsum;
    #pragma unroll
    for (int g = 0; g < 4; ++g)
        *(f32x4*)&acc_lds[(wq * 64 + lane) * 16 + g * 4] = acc[g];
    __syncthreads();

    // combine 4 waves, scatter partial numerator to global accumulator
    #pragma unroll
    for (int q = 0; q < 4; ++q) {
        const int e      = tid + q * 256;
        const int lane_e = e >> 4;
        const int k16    = e & 15;
        float s = 0.f;
        #pragma unroll
        for (int ww = 0; ww < 4; ++ww) s += acc_lds[(ww * 64 + lane_e) * 16 + k16];
        const int row = (lane_e >> 4) * 4 + (k16 & 3);   // C/D: row = quad*4+reg
        const int col = (k16 >> 2) * 16 + (lane_e & 15); // C/D: col = lane&15 (per n-group)
        unsafeAtomicAdd(&outAcc[(size_t)(i0 + row) * 64 + col], s);
    }
    if (tid < 16) {
        const float s = l_lds[tid] + l_lds[16 + tid] + l_lds[32 + tid] + l_lds[48 + tid];
        unsafeAtomicAdd(&lAcc[i0 + tid], s);
    }
}

// Kernel D: out = elu(numerator / denominator), in place
__global__ __launch_bounds__(256) void gat_final(
    float* __restrict__ out, const float* __restrict__ lAcc)
{
    const int idx = blockIdx.x * 256 + threadIdx.x;
    const float v = out[idx] / lAcc[idx >> 6];
    out[idx] = v > 0.f ? v : expm1f(v);
}

extern "C" void kernel_launch(void* const* d_in, const int* in_sizes, int n_in,
                              void* d_out, int out_size, void* d_ws, size_t ws_size,
                              hipStream_t stream) {
    const float* input = (const float*)d_in[0];   // 8192 x 512 f32
    const int*   adj   = (const int*)d_in[1];     // 8192 x 8192 i32
    const float* W     = (const float*)d_in[2];   // 512 x 64 f32
    const float* a     = (const float*)d_in[3];   // 128 x 1 f32
    float* out = (float*)d_out;                   // 8192 x 64 f32

    char* ws = (char*)d_ws;
    unsigned*       wsR  = (unsigned*)(ws + 0);          // 4 B   (ordered-uint max)
    float*          lAcc = (float*)(ws + 4096);          // 32 KB softmax denominators
    float*          attL = (float*)(ws + 36864);         // 32 KB
    float*          attR = (float*)(ws + 69632);         // 32 KB
    unsigned short* hThi = (unsigned short*)(ws + 102400);   // 1 MB  hT hi bf16
    unsigned short* hTlo = (unsigned short*)(ws + 1150976);  // 1 MB  hT lo bf16

    // zero the accumulators (ws/out are poisoned 0xAA before every call)
    hipMemsetAsync(d_out, 0, (size_t)out_size * sizeof(float), stream);
    hipMemsetAsync(d_ws, 0, 36864, stream);

    gat_prep<<<512, 256, 0, stream>>>(input, W, a, attL, attR, hThi, hTlo, wsR);
    gat_attn<<<2048, 256, 0, stream>>>(adj, attL, attR, hThi, hTlo, wsR, out, lAcc);
    gat_final<<<2048, 256, 0, stream>>>(out, lAcc);
}

// Round 4
// 443.071 us; speedup vs baseline: 1.3681x; 1.2730x over previous
//
#include <hip/hip_runtime.h>
#include <stdint.h>

#define ALPHA 0.2f
#define LOG2E 1.44269504088896340736f

typedef __attribute__((ext_vector_type(8))) short bf16x8;
typedef __attribute__((ext_vector_type(4))) float f32x4;

__device__ __forceinline__ unsigned short f2bf(float f) {
    unsigned u = __builtin_bit_cast(unsigned, f);
    u += 0x7fffu + ((u >> 16) & 1u);
    return (unsigned short)(u >> 16);
}
__device__ __forceinline__ float bf2f(unsigned short h) {
    unsigned u = ((unsigned)h) << 16;
    return __builtin_bit_cast(float, u);
}
// order-preserving float<->uint for atomicMax over signed floats (0 = -inf identity)
__device__ __forceinline__ unsigned f2ord(float f) {
    unsigned b = __builtin_bit_cast(unsigned, f);
    return (b & 0x80000000u) ? ~b : (b | 0x80000000u);
}
__device__ __forceinline__ float ord2f(unsigned k) {
    unsigned b = (k & 0x80000000u) ? (k & 0x7fffffffu) : ~k;
    return __builtin_bit_cast(float, b);
}

// ---------------------------------------------------------------------------
// Kernel 1: h = input @ W, fp32, k-split x4 with fp32 atomic accumulation.
// 2048 blocks (512 i-tiles x 4 k-splits) -> 8 blocks/CU. X staged in LDS
// (coalesced); W streamed coalesced from L2 (128 KB, shared by all blocks).
__global__ __launch_bounds__(256) void gat_h(
    const float* __restrict__ input, const float* __restrict__ W,
    float* __restrict__ h)
{
    __shared__ float x_lds[16 * 128];
    const int tid = threadIdx.x;
    const int i0  = (blockIdx.x >> 2) * 16;
    const int k0  = (blockIdx.x & 3) * 128;

    // stage X[i0..i0+16)[k0..k0+128): 8 KB, coalesced (16 rows x 512 B)
    {
        const int r  = tid >> 4;
        const int jc = (tid & 15) * 8;
        const float* src = input + (size_t)(i0 + r) * 512 + k0 + jc;
        *(f32x4*)&x_lds[r * 128 + jc]     = *(const f32x4*)src;
        *(f32x4*)&x_lds[r * 128 + jc + 4] = *(const f32x4*)(src + 4);
    }
    __syncthreads();

    const int c = tid & 63;   // output channel = lane
    const int w = tid >> 6;   // wave -> rows {w, w+4, w+8, w+12}
    float acc[4] = {0.f, 0.f, 0.f, 0.f};
    const float* Wc = W + (size_t)k0 * 64 + c;
    #pragma unroll 4
    for (int kk = 0; kk < 128; kk += 4) {
        const float w0 = Wc[(kk+0)*64], w1 = Wc[(kk+1)*64];
        const float w2 = Wc[(kk+2)*64], w3 = Wc[(kk+3)*64];
        #pragma unroll
        for (int ri = 0; ri < 4; ++ri) {
            const f32x4 x = *(const f32x4*)&x_lds[(w + 4*ri) * 128 + kk]; // broadcast
            acc[ri] += x.x * w0 + x.y * w1 + x.z * w2 + x.w * w3;
        }
    }
    #pragma unroll
    for (int ri = 0; ri < 4; ++ri)
        unsafeAtomicAdd(&h[(size_t)(i0 + w + 4*ri) * 64 + c], acc[ri]);
}

// ---------------------------------------------------------------------------
// Kernel 2: from h: attL/attR (row dots with a), R = global max(attR), and
// hPack = bf16 h^T in MFMA-B-fragment-major layout. One 32-j chunk per block:
//   hPack[(jc*4 + g)*512 + l*8 + u] = bf16(h[jc*32 + (l>>4)*8 + u][g*16 + (l&15)])
__global__ __launch_bounds__(256) void gat_aux(
    const float* __restrict__ h, const float* __restrict__ a,
    float* __restrict__ attL, float* __restrict__ attR,
    unsigned short* __restrict__ hPack, unsigned* __restrict__ wsR)
{
    __shared__ float hl[32 * 64];
    __shared__ unsigned rmax;
    const int tid = threadIdx.x;
    const int j0  = blockIdx.x * 32;     // jc = blockIdx.x
    if (tid == 0) rmax = 0u;

    // stage 32 h-rows (8 KB), coalesced
    {
        const float* src = h + (size_t)j0 * 64 + tid * 8;
        *(f32x4*)&hl[tid * 8]     = *(const f32x4*)src;
        *(f32x4*)&hl[tid * 8 + 4] = *(const f32x4*)(src + 4);
    }
    __syncthreads();

    // attL/attR: 8 threads per row, 8-c slices, shuffle-reduce
    {
        const int row = tid >> 3;
        const int cs  = (tid & 7) * 8;
        float pL = 0.f, pR = 0.f;
        #pragma unroll
        for (int u = 0; u < 8; ++u) {
            const float hv = hl[row * 64 + cs + u];
            pL += hv * a[cs + u];
            pR += hv * a[64 + cs + u];
        }
        pL += __shfl_xor(pL, 1, 64); pR += __shfl_xor(pR, 1, 64);
        pL += __shfl_xor(pL, 2, 64); pR += __shfl_xor(pR, 2, 64);
        pL += __shfl_xor(pL, 4, 64); pR += __shfl_xor(pR, 4, 64);
        if ((tid & 7) == 0) {
            attL[j0 + row] = pL;
            attR[j0 + row] = pR;
            atomicMax(&rmax, f2ord(pR));
        }
    }

    // hPack: 4 records (g = wave id), each thread emits one 16 B fragment slice
    {
        const int g = tid >> 6;          // c-group 0..3 (one per wave)
        const int l = tid & 63;
        const int m = l & 15;
        const int q = l >> 4;
        bf16x8 v;
        #pragma unroll
        for (int u = 0; u < 8; ++u)
            v[u] = (short)f2bf(hl[(q * 8 + u) * 64 + g * 16 + m]);
        *(bf16x8*)&hPack[(size_t)(blockIdx.x * 4 + g) * 512 + l * 8] = v;
    }

    __syncthreads();
    if (tid == 0) atomicMax(wsR, rmax);
}

// ---------------------------------------------------------------------------
// Kernel 3: pack adj into MFMA-A-fragment-major bitmask.
// adjU[(ti*64 + G)*64 + lane]: byte t (0..3) = chunk jc = G*4+t;
// bit u of byte = adj[ti*16 + (lane&15)][jc*32 + (lane>>4)*8 + u].
__global__ __launch_bounds__(256) void gat_pack(
    const int* __restrict__ adj, unsigned* __restrict__ adjU)
{
    __shared__ unsigned char pk[4096];
    const int tid = threadIdx.x;
    const int ti  = blockIdx.x >> 2;
    const int jq  = blockIdx.x & 3;
    const int r   = tid >> 4;
    const int jo  = (tid & 15) * 8;
    // byte (G_local=it, t=(tid&15)>>2, lane=(tid&3)*16+r) -> pk[it*256 + lane*4 + t]
    const int lidx_base = ((tid & 3) * 16 + r) * 4 + ((tid & 15) >> 2);

    const int* src = adj + (size_t)(ti * 16 + r) * 8192 + jq * 2048 + jo;
    #pragma unroll 4
    for (int it = 0; it < 16; ++it) {
        const int4 v0 = *(const int4*)(src + it * 128);
        const int4 v1 = *(const int4*)(src + it * 128 + 4);
        unsigned b = 0;
        b |= (v0.x != 0) << 0; b |= (v0.y != 0) << 1;
        b |= (v0.z != 0) << 2; b |= (v0.w != 0) << 3;
        b |= (v1.x != 0) << 4; b |= (v1.y != 0) << 5;
        b |= (v1.z != 0) << 6; b |= (v1.w != 0) << 7;
        pk[it * 256 + lidx_base] = (unsigned char)b;
    }
    __syncthreads();
    // write 4 KB coalesced: pk linear order == global byte order at (ti*64+jq*16)*256
    const uint4 o = *(const uint4*)&pk[tid * 16];
    *(uint4*)((unsigned char*)adjU + ((size_t)ti * 64 + jq * 16) * 256 + tid * 16) = o;
}

// ---------------------------------------------------------------------------
// Kernel 4: fused mask + exp + P@h via MFMA. Block: 16 i-rows x 2048 j.
// All loads wave-contiguous: bitmask uint / hPack fragments / broadcast attR.
__global__ __launch_bounds__(256, 8) void gat_attn(
    const unsigned* __restrict__ adjU,
    const float* __restrict__ attL, const float* __restrict__ attR,
    const unsigned short* __restrict__ hPack, const unsigned* __restrict__ wsR,
    float* __restrict__ outAcc, float* __restrict__ lAcc)
{
    __shared__ float acc_lds[4 * 64 * 16];
    __shared__ float l_lds[4 * 16];
    const int tid  = threadIdx.x;
    const int lane = tid & 63;
    const int wq   = tid >> 6;
    const int m    = lane & 15;
    const int quad = lane >> 4;
    const int ti   = blockIdx.x >> 2;
    const int q4   = blockIdx.x & 3;
    const int i0   = ti * 16;
    const int jc0  = q4 * 64 + wq * 16;     // first 32-j chunk of this wave

    const float R   = ord2f(*wsR);
    const float a_l = attL[i0 + m];
    const float t0  = a_l + R;
    const float M   = fmaxf(t0, ALPHA * t0);   // row upper bound (lrelu monotone)
    const float mc  = M * LOG2E;

    const unsigned*       ab_p = adjU + ((size_t)ti * 64 + (jc0 >> 2)) * 64 + lane;
    const float*          ar_p = attR + jc0 * 32 + quad * 8;
    const unsigned short* hp_p = hPack + (size_t)jc0 * 4 * 512 + lane * 8;

    f32x4 acc[4];
    #pragma unroll
    for (int g = 0; g < 4; ++g) acc[g] = (f32x4){0.f, 0.f, 0.f, 0.f};
    float lsum = 0.f;

    #pragma unroll
    for (int jg = 0; jg < 4; ++jg) {
        const unsigned ab = ab_p[jg * 64];      // 4 steps' bits, coalesced 256B
        #pragma unroll
        for (int t = 0; t < 4; ++t) {
            const int s = jg * 4 + t;
            const f32x4 r0 = *(const f32x4*)(ar_p + s * 32);
            const f32x4 r1 = *(const f32x4*)(ar_p + s * 32 + 4);
            bf16x8 B[4];
            #pragma unroll
            for (int g = 0; g < 4; ++g)
                B[g] = *(const bf16x8*)(hp_p + (size_t)(s * 4 + g) * 512);

            const unsigned bits = (ab >> (t * 8)) & 0xffu;
            const float tv[8] = { a_l + r0.x, a_l + r0.y, a_l + r0.z, a_l + r0.w,
                                  a_l + r1.x, a_l + r1.y, a_l + r1.z, a_l + r1.w };
            bf16x8 af;
            #pragma unroll
            for (int u = 0; u < 8; ++u) {
                const float e  = fmaxf(tv[u], ALPHA * tv[u]);        // leaky_relu
                const float pe = __builtin_amdgcn_exp2f(__builtin_fmaf(e, LOG2E, -mc));
                const float pv = (bits & (1u << u)) ? pe : 0.0f;     // mask
                const unsigned short pb = f2bf(pv);
                af[u] = (short)pb;
                lsum += bf2f(pb);   // denominator from the SAME rounded weights
            }
            #pragma unroll
            for (int g = 0; g < 4; ++g)
                acc[g] = __builtin_amdgcn_mfma_f32_16x16x32_bf16(af, B[g], acc[g], 0, 0, 0);
        }
    }

    // reduce l across the 4 k-quads (row m lives in lanes m, m+16, m+32, m+48)
    lsum += __shfl_xor(lsum, 16, 64);
    lsum += __shfl_xor(lsum, 32, 64);
    if (lane < 16) l_lds[wq * 16 + lane] = lsum;
    #pragma unroll
    for (int g = 0; g < 4; ++g)
        *(f32x4*)&acc_lds[(wq * 64 + lane) * 16 + g * 4] = acc[g];
    __syncthreads();

    // combine 4 waves, scatter partial numerator to global accumulator
    #pragma unroll
    for (int q = 0; q < 4; ++q) {
        const int e      = tid + q * 256;
        const int lane_e = e >> 4;
        const int k16    = e & 15;
        float s = 0.f;
        #pragma unroll
        for (int ww = 0; ww < 4; ++ww) s += acc_lds[(ww * 64 + lane_e) * 16 + k16];
        const int row = (lane_e >> 4) * 4 + (k16 & 3);   // C/D: row = quad*4+reg
        const int col = (k16 >> 2) * 16 + (lane_e & 15); // C/D: col = lane&15 per n-group
        unsafeAtomicAdd(&outAcc[(size_t)(i0 + row) * 64 + col], s);
    }
    if (tid < 16) {
        const float s = l_lds[tid] + l_lds[16 + tid] + l_lds[32 + tid] + l_lds[48 + tid];
        unsafeAtomicAdd(&lAcc[i0 + tid], s);
    }
}

// ---------------------------------------------------------------------------
// Kernel 5: out = elu(numerator / denominator)
__global__ __launch_bounds__(256) void gat_final(
    float* __restrict__ out, const float* __restrict__ lAcc)
{
    const int idx = blockIdx.x * 256 + threadIdx.x;
    const float v = out[idx] / lAcc[idx >> 6];
    out[idx] = v > 0.f ? v : (__builtin_amdgcn_exp2f(v * LOG2E) - 1.0f);
}

extern "C" void kernel_launch(void* const* d_in, const int* in_sizes, int n_in,
                              void* d_out, int out_size, void* d_ws, size_t ws_size,
                              hipStream_t stream) {
    const float* input = (const float*)d_in[0];   // 8192 x 512 f32
    const int*   adj   = (const int*)d_in[1];     // 8192 x 8192 i32
    const float* W     = (const float*)d_in[2];   // 512 x 64 f32
    const float* a     = (const float*)d_in[3];   // 128 x 1 f32
    float* out = (float*)d_out;                   // 8192 x 64 f32

    char* ws = (char*)d_ws;
    unsigned*       wsR   = (unsigned*)(ws + 0);            // 4 B    [zeroed]
    float*          lAcc  = (float*)(ws + 4096);            // 32 KB  [zeroed]
    float*          h     = (float*)(ws + 36864);           // 2 MB   [zeroed]
    float*          attL  = (float*)(ws + 2134016);         // 32 KB
    float*          attR  = (float*)(ws + 2166784);         // 32 KB
    unsigned short* hPack = (unsigned short*)(ws + 2199552);// 1 MB   fragment-major h^T bf16
    unsigned*       adjU  = (unsigned*)(ws + 3248128);      // 8 MB   fragment-major bitmask

    hipMemsetAsync(d_out, 0, (size_t)out_size * sizeof(float), stream);
    hipMemsetAsync(d_ws, 0, 2134016, stream);   // wsR + lAcc + h

    gat_pack <<<2048, 256, 0, stream>>>(adj, adjU);
    gat_h    <<<2048, 256, 0, stream>>>(input, W, h);
    gat_aux  <<< 256, 256, 0, stream>>>(h, a, attL, attR, hPack, wsR);
    gat_attn <<<2048, 256, 0, stream>>>(adjU, attL, attR, hPack, wsR, out, lAcc);
    gat_final<<<2048, 256, 0, stream>>>(out, lAcc);
}

// Round 5
// 415.413 us; speedup vs baseline: 1.4592x; 1.0666x over previous
//
#include <hip/hip_runtime.h>
#include <stdint.h>

#define ALPHA 0.2f
#define LOG2E 1.44269504088896340736f

typedef __attribute__((ext_vector_type(8))) short bf16x8;
typedef __attribute__((ext_vector_type(4))) float f32x4;

__device__ __forceinline__ unsigned short f2bf(float f) {
    unsigned u = __builtin_bit_cast(unsigned, f);
    u += 0x7fffu + ((u >> 16) & 1u);
    return (unsigned short)(u >> 16);
}
__device__ __forceinline__ float bf2f(unsigned short h) {
    unsigned u = ((unsigned)h) << 16;
    return __builtin_bit_cast(float, u);
}
// order-preserving float<->uint for atomicMax over signed floats (0 = -inf identity)
__device__ __forceinline__ unsigned f2ord(float f) {
    unsigned b = __builtin_bit_cast(unsigned, f);
    return (b & 0x80000000u) ? ~b : (b | 0x80000000u);
}
__device__ __forceinline__ float ord2f(unsigned k) {
    unsigned b = (k & 0x80000000u) ? (k & 0x7fffffffu) : ~k;
    return __builtin_bit_cast(float, b);
}

// ---------------------------------------------------------------------------
// Kernel 1: h = input @ W, fp32, k-split x4 with fp32 atomic accumulation.
__global__ __launch_bounds__(256) void gat_h(
    const float* __restrict__ input, const float* __restrict__ W,
    float* __restrict__ h)
{
    __shared__ float x_lds[16 * 128];
    const int tid = threadIdx.x;
    const int i0  = (blockIdx.x >> 2) * 16;
    const int k0  = (blockIdx.x & 3) * 128;

    {
        const int r  = tid >> 4;
        const int jc = (tid & 15) * 8;
        const float* src = input + (size_t)(i0 + r) * 512 + k0 + jc;
        *(f32x4*)&x_lds[r * 128 + jc]     = *(const f32x4*)src;
        *(f32x4*)&x_lds[r * 128 + jc + 4] = *(const f32x4*)(src + 4);
    }
    __syncthreads();

    const int c = tid & 63;
    const int w = tid >> 6;
    float acc[4] = {0.f, 0.f, 0.f, 0.f};
    const float* Wc = W + (size_t)k0 * 64 + c;
    #pragma unroll 4
    for (int kk = 0; kk < 128; kk += 4) {
        const float w0 = Wc[(kk+0)*64], w1 = Wc[(kk+1)*64];
        const float w2 = Wc[(kk+2)*64], w3 = Wc[(kk+3)*64];
        #pragma unroll
        for (int ri = 0; ri < 4; ++ri) {
            const f32x4 x = *(const f32x4*)&x_lds[(w + 4*ri) * 128 + kk];
            acc[ri] += x.x * w0 + x.y * w1 + x.z * w2 + x.w * w3;
        }
    }
    #pragma unroll
    for (int ri = 0; ri < 4; ++ri)
        unsafeAtomicAdd(&h[(size_t)(i0 + w + 4*ri) * 64 + c], acc[ri]);
}

// ---------------------------------------------------------------------------
// Kernel 2: attL/attR, R = max(attR), hPack (MFMA-B-fragment-major bf16 h^T).
__global__ __launch_bounds__(256) void gat_aux(
    const float* __restrict__ h, const float* __restrict__ a,
    float* __restrict__ attL, float* __restrict__ attR,
    unsigned short* __restrict__ hPack, unsigned* __restrict__ wsR)
{
    __shared__ float hl[32 * 64];
    __shared__ unsigned rmax;
    const int tid = threadIdx.x;
    const int j0  = blockIdx.x * 32;
    if (tid == 0) rmax = 0u;

    {
        const float* src = h + (size_t)j0 * 64 + tid * 8;
        *(f32x4*)&hl[tid * 8]     = *(const f32x4*)src;
        *(f32x4*)&hl[tid * 8 + 4] = *(const f32x4*)(src + 4);
    }
    __syncthreads();

    {
        const int row = tid >> 3;
        const int cs  = (tid & 7) * 8;
        float pL = 0.f, pR = 0.f;
        #pragma unroll
        for (int u = 0; u < 8; ++u) {
            const float hv = hl[row * 64 + cs + u];
            pL += hv * a[cs + u];
            pR += hv * a[64 + cs + u];
        }
        pL += __shfl_xor(pL, 1, 64); pR += __shfl_xor(pR, 1, 64);
        pL += __shfl_xor(pL, 2, 64); pR += __shfl_xor(pR, 2, 64);
        pL += __shfl_xor(pL, 4, 64); pR += __shfl_xor(pR, 4, 64);
        if ((tid & 7) == 0) {
            attL[j0 + row] = pL;
            attR[j0 + row] = pR;
            atomicMax(&rmax, f2ord(pR));
        }
    }

    {
        const int g = tid >> 6;
        const int l = tid & 63;
        const int m = l & 15;
        const int q = l >> 4;
        bf16x8 v;
        #pragma unroll
        for (int u = 0; u < 8; ++u)
            v[u] = (short)f2bf(hl[(q * 8 + u) * 64 + g * 16 + m]);
        *(bf16x8*)&hPack[(size_t)(blockIdx.x * 4 + g) * 512 + l * 8] = v;
    }

    __syncthreads();
    if (tid == 0) atomicMax(wsR, rmax);
}

// ---------------------------------------------------------------------------
// Kernel 3 (FUSED pack+attn): reads raw adj coalesced, packs bitmask into LDS
// (per-wave 1 KB bit regions at 4 KB stride, aliasing each wave's own later
// acc-epilogue region), then identical phase-2 MFMA loop as R4.
// Block: 16 i-rows x 2048 j. 2048 blocks -> 8 blocks/CU; LDS 16.25 KB.
__global__ __launch_bounds__(256, 8) void gat_attn(
    const int* __restrict__ adj,
    const float* __restrict__ attL, const float* __restrict__ attR,
    const unsigned short* __restrict__ hPack, const unsigned* __restrict__ wsR,
    float* __restrict__ outAcc, float* __restrict__ lAcc)
{
    __shared__ unsigned smem[4096];   // phase1: bitmask words; phase2 epilogue: acc floats
    __shared__ float l_lds[64];
    const int tid  = threadIdx.x;
    const int lane = tid & 63;
    const int wq   = tid >> 6;
    const int m    = lane & 15;
    const int quad = lane >> 4;
    const int ti   = blockIdx.x >> 2;
    const int q4   = blockIdx.x & 3;
    const int i0   = ti * 16;
    const int jc0  = q4 * 64 + wq * 16;     // wave's first 32-j chunk (global units)

    // ---- phase 1: pack adj[i0..i0+16)[q4*2048..+2048) -> LDS bitmask ----
    // thread covers row r = tid>>4, col octets (tid&15)*8 + it*128.
    // byte (G_local=it, t=(tid&15)>>2, frag-lane=(tid&3)*16+r) stored at
    // uint (it>>2)*1024 + (it&3)*64 + lane, byte t.  (R4-verified mapping)
    {
        const int r    = tid >> 4;
        const int lidx = (tid & 3) * 16 + r;
        const int t    = (tid & 15) >> 2;
        unsigned char* bb = (unsigned char*)smem;
        const int* src = adj + (size_t)(i0 + r) * 8192 + q4 * 2048 + (tid & 15) * 8;
        #pragma unroll 4
        for (int it = 0; it < 16; ++it) {
            const int4 v0 = *(const int4*)(src + it * 128);
            const int4 v1 = *(const int4*)(src + it * 128 + 4);
            unsigned b = 0;
            b |= (v0.x != 0) << 0; b |= (v0.y != 0) << 1;
            b |= (v0.z != 0) << 2; b |= (v0.w != 0) << 3;
            b |= (v1.x != 0) << 4; b |= (v1.y != 0) << 5;
            b |= (v1.z != 0) << 6; b |= (v1.w != 0) << 7;
            bb[((((it >> 2) * 1024) + (it & 3) * 64 + lidx) << 2) + t] = (unsigned char)b;
        }
    }
    __syncthreads();

    // preload this wave's 4 bit-words (its own 1 KB region; safe to overwrite
    // later by its own acc epilogue — program order within the wave)
    unsigned abw[4];
    #pragma unroll
    for (int g4 = 0; g4 < 4; ++g4)
        abw[g4] = smem[wq * 1024 + g4 * 64 + lane];

    const float R   = ord2f(*wsR);
    const float a_l = attL[i0 + m];
    const float t0  = a_l + R;
    const float M   = fmaxf(t0, ALPHA * t0);   // row upper bound (lrelu monotone)
    const float mc  = M * LOG2E;

    const float*          ar_p = attR + jc0 * 32 + quad * 8;
    const unsigned short* hp_p = hPack + (size_t)jc0 * 4 * 512 + lane * 8;

    f32x4 acc[4];
    #pragma unroll
    for (int g = 0; g < 4; ++g) acc[g] = (f32x4){0.f, 0.f, 0.f, 0.f};
    float lsum = 0.f;

    #pragma unroll
    for (int jg = 0; jg < 4; ++jg) {
        const unsigned ab = abw[jg];            // 4 steps' bits
        #pragma unroll
        for (int t = 0; t < 4; ++t) {
            const int s = jg * 4 + t;
            const f32x4 r0 = *(const f32x4*)(ar_p + s * 32);
            const f32x4 r1 = *(const f32x4*)(ar_p + s * 32 + 4);
            bf16x8 B[4];
            #pragma unroll
            for (int g = 0; g < 4; ++g)
                B[g] = *(const bf16x8*)(hp_p + (size_t)(s * 4 + g) * 512);

            const unsigned bits = (ab >> (t * 8)) & 0xffu;
            const float tv[8] = { a_l + r0.x, a_l + r0.y, a_l + r0.z, a_l + r0.w,
                                  a_l + r1.x, a_l + r1.y, a_l + r1.z, a_l + r1.w };
            bf16x8 af;
            #pragma unroll
            for (int u = 0; u < 8; ++u) {
                const float e  = fmaxf(tv[u], ALPHA * tv[u]);        // leaky_relu
                const float pe = __builtin_amdgcn_exp2f(__builtin_fmaf(e, LOG2E, -mc));
                const float pv = (bits & (1u << u)) ? pe : 0.0f;     // mask
                const unsigned short pb = f2bf(pv);
                af[u] = (short)pb;
                lsum += bf2f(pb);   // denominator from the SAME rounded weights
            }
            #pragma unroll
            for (int g = 0; g < 4; ++g)
                acc[g] = __builtin_amdgcn_mfma_f32_16x16x32_bf16(af, B[g], acc[g], 0, 0, 0);
        }
    }

    // reduce l across the 4 k-quads (row m lives in lanes m, m+16, m+32, m+48)
    lsum += __shfl_xor(lsum, 16, 64);
    lsum += __shfl_xor(lsum, 32, 64);
    if (lane < 16) l_lds[wq * 16 + lane] = lsum;
    // epilogue: wave wq writes floats [wq*1024, +1024) — its own aliased region
    float* accf = (float*)smem;
    #pragma unroll
    for (int g = 0; g < 4; ++g)
        *(f32x4*)&accf[(wq * 64 + lane) * 16 + g * 4] = acc[g];
    __syncthreads();

    // combine 4 waves, scatter partial numerator to global accumulator
    #pragma unroll
    for (int q = 0; q < 4; ++q) {
        const int e      = tid + q * 256;
        const int lane_e = e >> 4;
        const int k16    = e & 15;
        float s = 0.f;
        #pragma unroll
        for (int ww = 0; ww < 4; ++ww) s += accf[(ww * 64 + lane_e) * 16 + k16];
        const int row = (lane_e >> 4) * 4 + (k16 & 3);   // C/D: row = quad*4+reg
        const int col = (k16 >> 2) * 16 + (lane_e & 15); // C/D: col = lane&15 per n-group
        unsafeAtomicAdd(&outAcc[(size_t)(i0 + row) * 64 + col], s);
    }
    if (tid < 16) {
        const float s = l_lds[tid] + l_lds[16 + tid] + l_lds[32 + tid] + l_lds[48 + tid];
        unsafeAtomicAdd(&lAcc[i0 + tid], s);
    }
}

// ---------------------------------------------------------------------------
// Kernel 4: out = elu(numerator / denominator)
__global__ __launch_bounds__(256) void gat_final(
    float* __restrict__ out, const float* __restrict__ lAcc)
{
    const int idx = blockIdx.x * 256 + threadIdx.x;
    const float v = out[idx] / lAcc[idx >> 6];
    out[idx] = v > 0.f ? v : (__builtin_amdgcn_exp2f(v * LOG2E) - 1.0f);
}

extern "C" void kernel_launch(void* const* d_in, const int* in_sizes, int n_in,
                              void* d_out, int out_size, void* d_ws, size_t ws_size,
                              hipStream_t stream) {
    const float* input = (const float*)d_in[0];   // 8192 x 512 f32
    const int*   adj   = (const int*)d_in[1];     // 8192 x 8192 i32
    const float* W     = (const float*)d_in[2];   // 512 x 64 f32
    const float* a     = (const float*)d_in[3];   // 128 x 1 f32
    float* out = (float*)d_out;                   // 8192 x 64 f32

    char* ws = (char*)d_ws;
    unsigned*       wsR   = (unsigned*)(ws + 0);            // 4 B    [zeroed]
    float*          lAcc  = (float*)(ws + 4096);            // 32 KB  [zeroed]
    float*          h     = (float*)(ws + 36864);           // 2 MB   [zeroed]
    float*          attL  = (float*)(ws + 2134016);         // 32 KB
    float*          attR  = (float*)(ws + 2166784);         // 32 KB
    unsigned short* hPack = (unsigned short*)(ws + 2199552);// 1 MB   fragment-major h^T bf16

    hipMemsetAsync(d_out, 0, (size_t)out_size * sizeof(float), stream);
    hipMemsetAsync(d_ws, 0, 2134016, stream);   // wsR + lAcc + h

    gat_h    <<<2048, 256, 0, stream>>>(input, W, h);
    gat_aux  <<< 256, 256, 0, stream>>>(h, a, attL, attR, hPack, wsR);
    gat_attn <<<2048, 256, 0, stream>>>(adj, attL, attR, hPack, wsR, out, lAcc);
    gat_final<<<2048, 256, 0, stream>>>(out, lAcc);
}